// Round 2
// baseline (550.132 us; speedup 1.0000x reference)
//
#include <hip/hip_runtime.h>

typedef __bf16 bf16;
typedef __attribute__((ext_vector_type(4))) bf16 bf16x4;
typedef __attribute__((ext_vector_type(8))) bf16 bf16x8;
typedef __attribute__((ext_vector_type(4))) float f32x4;
typedef __attribute__((ext_vector_type(4))) int i32x4;

#define MFMA_BF16(a, b, c) __builtin_amdgcn_mfma_f32_16x16x32_bf16((a), (b), (c), 0, 0, 0)

constexpr int S_LEN = 2048;
constexpr int EMB   = 1024;
constexpr int NHEAD = 16;
constexpr int HDIM  = 64;
constexpr int BATCH = 4;
constexpr int NTOK  = BATCH * S_LEN;   // 8192

// async global->LDS, 16B per lane (m97 pattern: LDS dest must be uniform base + lane*16)
__device__ __forceinline__ void gload_lds16(const bf16* g, bf16* l) {
    __builtin_amdgcn_global_load_lds(
        (const __attribute__((address_space(1))) void*)g,
        (__attribute__((address_space(3))) void*)l, 16, 0, 0);
}

// ---------------------------------------------------------------------------
// fp32 -> bf16 elementwise convert (n4 = n/4)
// ---------------------------------------------------------------------------
__global__ __launch_bounds__(256)
void cvt_f32_bf16(const float* __restrict__ src, bf16* __restrict__ dst, int n4) {
    int i = blockIdx.x * 256 + threadIdx.x;
    if (i < n4) {
        f32x4 v = ((const f32x4*)src)[i];
        bf16x4 o;
        o[0] = (bf16)v[0]; o[1] = (bf16)v[1]; o[2] = (bf16)v[2]; o[3] = (bf16)v[3];
        ((bf16x4*)dst)[i] = o;
    }
}

// ---------------------------------------------------------------------------
// NT GEMM, m97 structure: C[M,N] = A[M,K]*W[N,K]^T + bias. 128x128 tile, BK=32,
// 256 thr = 4 waves 2x2 (64x64 each). global_load_lds(16B) staging, unpadded
// 64B LDS rows. fused=1: grid (64,24), seg = y>>3 picks {Q,K,V}; V scatters to
// Vt[b,h,d,s] with packed 8B stores. fused=0: grid (64,8), fp32 output.
// q_scale: folded into the Q output (seg==0) so flash_attn's softmax needs no
// per-element scale multiply.
// ---------------------------------------------------------------------------
__global__ __launch_bounds__(256)
void gemm_bt(const bf16* __restrict__ A,
             const bf16* __restrict__ W0, const bf16* __restrict__ W1, const bf16* __restrict__ W2,
             const float* __restrict__ b0, const float* __restrict__ b1, const float* __restrict__ b2,
             void* __restrict__ d0, void* __restrict__ d1, void* __restrict__ d2,
             int fused, float q_scale)
{
    __shared__ bf16 al[128 * 32];
    __shared__ bf16 bl[128 * 32];

    int seg, mode, n0;
    if (fused) { seg = blockIdx.y >> 3; n0 = (blockIdx.y & 7) * 128; mode = (seg == 2) ? 1 : 0; }
    else       { seg = 0;              n0 = blockIdx.y * 128;        mode = 2; }
    const bf16*  W    = seg == 0 ? W0 : (seg == 1 ? W1 : W2);
    const float* bias = seg == 0 ? b0 : (seg == 1 ? b1 : b2);
    void*        C    = seg == 0 ? d0 : (seg == 1 ? d1 : d2);
    const float  osc  = (fused && seg == 0) ? q_scale : 1.0f;

    const int tid  = threadIdx.x;
    const int lane = tid & 63;
    const int w    = tid >> 6;
    const int quad = lane >> 4;
    const int l16  = lane & 15;
    const int wm   = (w >> 1) * 64;
    const int wn   = (w & 1) * 64;
    const int m0   = blockIdx.x * 128;

    f32x4 acc[4][4] = {};

    for (int k0 = 0; k0 < EMB; k0 += 32) {
        #pragma unroll
        for (int c = 0; c < 2; ++c) {
            int idx = c * 256 + tid;            // LDS addr = idx*16B: uniform base + lane*16 per wave
            int row = idx >> 2, kc = idx & 3;
            gload_lds16(A + (size_t)(m0 + row) * EMB + k0 + kc * 8, &al[idx * 8]);
            gload_lds16(W + (size_t)(n0 + row) * EMB + k0 + kc * 8, &bl[idx * 8]);
        }
        __syncthreads();

        bf16x8 afrag[4], bfrag[4];
        #pragma unroll
        for (int t = 0; t < 4; ++t)
            afrag[t] = *(const bf16x8*)&al[(wm + t * 16 + l16) * 32 + quad * 8];
        #pragma unroll
        for (int t = 0; t < 4; ++t)
            bfrag[t] = *(const bf16x8*)&bl[(wn + t * 16 + l16) * 32 + quad * 8];

        #pragma unroll
        for (int mt = 0; mt < 4; ++mt)
            #pragma unroll
            for (int nt = 0; nt < 4; ++nt)
                acc[mt][nt] = MFMA_BF16(afrag[mt], bfrag[nt], acc[mt][nt]);

        __syncthreads();
    }

    // epilogue: C-layout row = quad*4+r, col = l16 (m89-verified)
    #pragma unroll
    for (int mt = 0; mt < 4; ++mt) {
        #pragma unroll
        for (int nt = 0; nt < 4; ++nt) {
            int col = n0 + wn + nt * 16 + l16;
            float bv = bias[col];
            int row0 = m0 + wm + mt * 16 + quad * 4;
            if (mode == 1) {
                int bb = row0 >> 11, s0 = row0 & 2047;
                int hh = col >> 6,   d  = col & 63;
                bf16x4 pk;
                #pragma unroll
                for (int r = 0; r < 4; ++r) pk[r] = (bf16)(acc[mt][nt][r] + bv);
                *(bf16x4*)((bf16*)C + (size_t)((bb * NHEAD + hh) * HDIM + d) * S_LEN + s0) = pk;
            } else if (mode == 0) {
                #pragma unroll
                for (int r = 0; r < 4; ++r)
                    ((bf16*)C)[(size_t)(row0 + r) * EMB + col] = (bf16)((acc[mt][nt][r] + bv) * osc);
            } else {
                #pragma unroll
                for (int r = 0; r < 4; ++r)
                    ((float*)C)[(size_t)(row0 + r) * EMB + col] = acc[mt][nt][r] + bv;
            }
        }
    }
}

// ---------------------------------------------------------------------------
// Flash attention, S^T orientation: sacc = mfma(kf, qf) so C-layout puts
// query on l16 (lane) and keys on (nt, quad*4+r) regs. Q is PRE-SCALED by
// 1/sqrt(64)*log2e in the QKV GEMM, so softmax works on raw sacc.
//
// Round-1 lesson (counters): __launch_bounds__(256,4) halved the arch-VGPR
// budget (unified VGPR/AGPR file) -> sacc spilled to scratch: VGPR 120->64,
// FETCH 139->428MB, WRITE 16->217MB, dur 251->340us. Occupancy bought with
// spills is a net loss. So: plain __launch_bounds__(256); LDS kept at 37.9KB
// so 4 blocks/CU remains reachable if the allocator lands <=128 VGPR.
//
// Kept from round 1 (all softmax-side wins):
//  - allvalid (block-uniform) mask flag: all-ones mask skips the bias pass.
//  - defer-max (THR=8): skip alpha/oacc-rescale/stat_lds round-trip when the
//    tile max stayed within 8 of the running max (P bounded by 2^8, safe).
//  - per-lane partial l (alpha is quad-uniform) -> row-sum shuffles once.
//  - plds: 256B rows + XOR swizzle (byte ^= (l16&7)<<4) on write AND read.
//  - s_setprio(1) around both MFMA clusters (T5).
// No in-loop __syncthreads (all LDS regions wave-private; wave64 lockstep).
// Grid (S/128, H, B), 256 thr = 4 waves; wave owns 32 query rows.
// ---------------------------------------------------------------------------
__global__ __launch_bounds__(256)
void flash_attn(const bf16* __restrict__ qg, const bf16* __restrict__ kg,
                const bf16* __restrict__ vtg, const int* __restrict__ maskg,
                bf16* __restrict__ ctx)
{
    __shared__ bf16  plds[128 * 128];     // 256B rows, XOR-swizzled, 32KB
    __shared__ bf16  bias_lds[2048];      // additive mask bias (bf16), masked path only
    __shared__ float stat_lds[4][32];     // per-wave alpha / inv-l broadcast

    const int tid  = threadIdx.x;
    const int lane = tid & 63;
    const int w    = tid >> 6;
    const int quad = lane >> 4;
    const int l16  = lane & 15;
    const int b    = blockIdx.z;
    const int h    = blockIdx.y;
    const int q0   = blockIdx.x * 128;

    // mask -> bf16 additive bias in LDS (each thread covers 8 keys) + allvalid
    int ok;
    {
        int i = tid * 8;
        i32x4 m0v = *(const i32x4*)(maskg + b * S_LEN + i);
        i32x4 m1v = *(const i32x4*)(maskg + b * S_LEN + i + 4);
        bf16x8 bb;
        ok = 1;
        #pragma unroll
        for (int r = 0; r < 4; ++r) {
            ok &= (m0v[r] != 0) & (m1v[r] != 0);
            bb[r]     = m0v[r] ? (bf16)0.f : (bf16)(-3.0e38f);
            bb[4 + r] = m1v[r] ? (bf16)0.f : (bf16)(-3.0e38f);
        }
        *(bf16x8*)&bias_lds[i] = bb;
    }
    const int allvalid = __syncthreads_and(ok);

    // Q fragments (B-operand: n=query=l16, k=quad*8+j), resident all kernel
    bf16x8 qf[2][2];
    #pragma unroll
    for (int mt = 0; mt < 2; ++mt)
        #pragma unroll
        for (int ks = 0; ks < 2; ++ks) {
            int row = b * S_LEN + q0 + w * 32 + mt * 16 + l16;
            qf[mt][ks] = *(const bf16x8*)(qg + (size_t)row * EMB + h * HDIM + ks * 32 + quad * 8);
        }

    float mrow[2]  = {-1e30f, -1e30f};
    float lpart[2] = {0.f, 0.f};          // per-lane partial row-sum (quad-partial)
    f32x4 oacc[2][4] = {};

    for (int kt = 0; kt < 16; ++kt) {
        const int k0 = kt * 128;

        // ---- S^T = K Q^T: C[key=quad*4+r][query=l16] per (nt,mt) tile ----
        f32x4 sacc[8][2] = {};
        __builtin_amdgcn_s_setprio(1);
        #pragma unroll
        for (int nt = 0; nt < 8; ++nt) {
            int krow = b * S_LEN + k0 + nt * 16 + l16;
            #pragma unroll
            for (int ks = 0; ks < 2; ++ks) {
                bf16x8 kf = *(const bf16x8*)(kg + (size_t)krow * EMB + h * HDIM + ks * 32 + quad * 8);
                sacc[nt][0] = MFMA_BF16(kf, qf[0][ks], sacc[nt][0]);
                sacc[nt][1] = MFMA_BF16(kf, qf[1][ks], sacc[nt][1]);
            }
        }
        __builtin_amdgcn_s_setprio(0);

        // ---- row max over keys (bias pass only when mask has zeros) ----
        float rmax[2] = {-3.0e38f, -3.0e38f};
        if (allvalid) {
            #pragma unroll
            for (int nt = 0; nt < 8; ++nt)
                #pragma unroll
                for (int mt = 0; mt < 2; ++mt)
                    rmax[mt] = fmaxf(rmax[mt],
                                     fmaxf(fmaxf(sacc[nt][mt][0], sacc[nt][mt][1]),
                                           fmaxf(sacc[nt][mt][2], sacc[nt][mt][3])));
        } else {
            #pragma unroll
            for (int nt = 0; nt < 8; ++nt) {
                bf16x4 b4 = *(const bf16x4*)&bias_lds[k0 + nt * 16 + quad * 4];
                #pragma unroll
                for (int mt = 0; mt < 2; ++mt)
                    #pragma unroll
                    for (int r = 0; r < 4; ++r) {
                        float sv = sacc[nt][mt][r] + (float)b4[r];
                        sacc[nt][mt][r] = sv;
                        rmax[mt] = fmaxf(rmax[mt], sv);
                    }
            }
        }
        #pragma unroll
        for (int mt = 0; mt < 2; ++mt) {
            rmax[mt] = fmaxf(rmax[mt], __shfl_xor(rmax[mt], 16));
            rmax[mt] = fmaxf(rmax[mt], __shfl_xor(rmax[mt], 32));
        }

        // ---- defer-max: rescale only when running max grew by > 8 ----
        if (!__all((rmax[0] <= mrow[0] + 8.f) & (rmax[1] <= mrow[1] + 8.f))) {
            float alpha[2];
            #pragma unroll
            for (int mt = 0; mt < 2; ++mt) {
                float mnew = fmaxf(mrow[mt], rmax[mt]);
                alpha[mt] = __builtin_amdgcn_exp2f(mrow[mt] - mnew);
                mrow[mt]  = mnew;
                lpart[mt] *= alpha[mt];
            }
            if (quad == 0) { stat_lds[w][l16] = alpha[0]; stat_lds[w][16 + l16] = alpha[1]; }
            #pragma unroll
            for (int mt2 = 0; mt2 < 2; ++mt2) {
                f32x4 a4 = *(const f32x4*)&stat_lds[w][mt2 * 16 + quad * 4];
                #pragma unroll
                for (int dt = 0; dt < 4; ++dt)
                    #pragma unroll
                    for (int r = 0; r < 4; ++r)
                        oacc[mt2][dt][r] *= a4[r];
            }
        }

        // ---- P = exp2(S - m), packed bf16 writes to swizzled LDS ----
        #pragma unroll
        for (int nt = 0; nt < 8; ++nt)
            #pragma unroll
            for (int mt = 0; mt < 2; ++mt) {
                bf16x4 pk;
                #pragma unroll
                for (int r = 0; r < 4; ++r) {
                    float p = __builtin_amdgcn_exp2f(sacc[nt][mt][r] - mrow[mt]);
                    lpart[mt] += p;
                    pk[r] = (bf16)p;
                }
                int byte = (w * 32 + mt * 16 + l16) * 256 + nt * 32 + quad * 8;
                byte ^= (l16 & 7) << 4;
                *(bf16x4*)((char*)plds + byte) = pk;
            }

        // ---- O += P V  (P A-operand from swizzled LDS b128, Vt NT B-operand) ----
        __builtin_amdgcn_s_setprio(1);
        #pragma unroll
        for (int ks = 0; ks < 4; ++ks) {
            int byte0 = (w * 32 + l16) * 256 + ks * 64 + quad * 16;
            byte0 ^= (l16 & 7) << 4;
            bf16x8 pf0 = *(const bf16x8*)((char*)plds + byte0);
            bf16x8 pf1 = *(const bf16x8*)((char*)plds + byte0 + 16 * 256);
            #pragma unroll
            for (int dt = 0; dt < 4; ++dt) {
                bf16x8 vf = *(const bf16x8*)(vtg + (size_t)((b * NHEAD + h) * HDIM + dt * 16 + l16) * S_LEN
                                             + k0 + ks * 32 + quad * 8);
                oacc[0][dt] = MFMA_BF16(pf0, vf, oacc[0][dt]);
                oacc[1][dt] = MFMA_BF16(pf1, vf, oacc[1][dt]);
            }
        }
        __builtin_amdgcn_s_setprio(0);
    }

    // ---- final cross-quad row-sum reduce, 1/l broadcast, store ctx[b,s,h,d] ----
    float lrow[2];
    #pragma unroll
    for (int mt = 0; mt < 2; ++mt) {
        float s = lpart[mt];
        s += __shfl_xor(s, 16);
        s += __shfl_xor(s, 32);
        lrow[mt] = s;
    }
    if (quad == 0) {
        stat_lds[w][l16]      = lrow[0] > 0.f ? 1.f / lrow[0] : 0.f;
        stat_lds[w][16 + l16] = lrow[1] > 0.f ? 1.f / lrow[1] : 0.f;
    }
    #pragma unroll
    for (int mt2 = 0; mt2 < 2; ++mt2) {
        f32x4 inv4 = *(const f32x4*)&stat_lds[w][mt2 * 16 + quad * 4];
        #pragma unroll
        for (int r = 0; r < 4; ++r) {
            size_t row = (size_t)(b * S_LEN + q0 + w * 32 + mt2 * 16 + quad * 4 + r);
            #pragma unroll
            for (int dt = 0; dt < 4; ++dt)
                ctx[row * EMB + h * HDIM + dt * 16 + l16] = (bf16)(oacc[mt2][dt][r] * inv4[r]);
        }
    }
}

extern "C" void kernel_launch(void* const* d_in, const int* in_sizes, int n_in,
                              void* d_out, int out_size, void* d_ws, size_t ws_size,
                              hipStream_t stream)
{
    const float* x   = (const float*)d_in[0];
    const int*  mask = (const int*)d_in[1];
    const float* Wq  = (const float*)d_in[2];
    const float* bq  = (const float*)d_in[3];
    const float* Wk  = (const float*)d_in[4];
    const float* bk  = (const float*)d_in[5];
    const float* Wv  = (const float*)d_in[6];
    const float* bv  = (const float*)d_in[7];
    const float* Wo  = (const float*)d_in[8];
    const float* bo  = (const float*)d_in[9];
    (void)in_sizes; (void)n_in; (void)out_size; (void)ws_size;

    const size_t me = (size_t)NTOK * EMB;    // 8.4M
    const size_t we = (size_t)EMB * EMB;     // 1M
    bf16* xb  = (bf16*)d_ws;
    bf16* qb  = xb  + me;
    bf16* kb  = qb  + me;
    bf16* vt  = kb  + me;     // V transposed [b,h,d,s]
    bf16* wqb = vt  + me;
    bf16* wkb = wqb + we;
    bf16* wvb = wkb + we;
    bf16* wob = wvb + we;
    bf16* cx  = xb;           // alias: xb consumed by qkv gemm before flash writes cx

    cvt_f32_bf16<<<(int)(me / 4 / 256), 256, 0, stream>>>(x,  xb,  (int)(me / 4));
    cvt_f32_bf16<<<(int)(we / 4 / 256), 256, 0, stream>>>(Wq, wqb, (int)(we / 4));
    cvt_f32_bf16<<<(int)(we / 4 / 256), 256, 0, stream>>>(Wk, wkb, (int)(we / 4));
    cvt_f32_bf16<<<(int)(we / 4 / 256), 256, 0, stream>>>(Wv, wvb, (int)(we / 4));
    cvt_f32_bf16<<<(int)(we / 4 / 256), 256, 0, stream>>>(Wo, wob, (int)(we / 4));

    // q_scale = 1/sqrt(HDIM) * log2(e), folded into Q so flash softmax is scale-free
    gemm_bt<<<dim3(NTOK / 128, 24), 256, 0, stream>>>(
        xb, wqb, wkb, wvb, bq, bk, bv, qb, kb, vt, 1, 0.18033688011112042f);

    flash_attn<<<dim3(S_LEN / 128, NHEAD, BATCH), 256, 0, stream>>>(qb, kb, vt, mask, cx);

    gemm_bt<<<dim3(NTOK / 128, EMB / 128), 256, 0, stream>>>(
        cx, wob, wob, wob, bo, bo, bo, d_out, d_out, d_out, 0, 1.0f);
}

// Round 3
// 465.147 us; speedup vs baseline: 1.1827x; 1.1827x over previous
//
#include <hip/hip_runtime.h>

typedef __bf16 bf16;
typedef __attribute__((ext_vector_type(4))) bf16 bf16x4;
typedef __attribute__((ext_vector_type(8))) bf16 bf16x8;
typedef __attribute__((ext_vector_type(4))) float f32x4;
typedef __attribute__((ext_vector_type(4))) int i32x4;

#define MFMA_BF16(a, b, c) __builtin_amdgcn_mfma_f32_16x16x32_bf16((a), (b), (c), 0, 0, 0)

constexpr int S_LEN = 2048;
constexpr int EMB   = 1024;
constexpr int NHEAD = 16;
constexpr int HDIM  = 64;
constexpr int BATCH = 4;
constexpr int NTOK  = BATCH * S_LEN;   // 8192

// async global->LDS, 16B per lane (m97 pattern: LDS dest must be uniform base + lane*16)
__device__ __forceinline__ void gload_lds16(const bf16* g, bf16* l) {
    __builtin_amdgcn_global_load_lds(
        (const __attribute__((address_space(1))) void*)g,
        (__attribute__((address_space(3))) void*)l, 16, 0, 0);
}

// ---------------------------------------------------------------------------
// fp32 -> bf16 elementwise convert (n4 = n/4)
// ---------------------------------------------------------------------------
__global__ __launch_bounds__(256)
void cvt_f32_bf16(const float* __restrict__ src, bf16* __restrict__ dst, int n4) {
    int i = blockIdx.x * 256 + threadIdx.x;
    if (i < n4) {
        f32x4 v = ((const f32x4*)src)[i];
        bf16x4 o;
        o[0] = (bf16)v[0]; o[1] = (bf16)v[1]; o[2] = (bf16)v[2]; o[3] = (bf16)v[3];
        ((bf16x4*)dst)[i] = o;
    }
}

// ---------------------------------------------------------------------------
// NT GEMM, m97 structure: C[M,N] = A[M,K]*W[N,K]^T + bias. 128x128 tile, BK=32,
// 256 thr = 4 waves 2x2 (64x64 each). global_load_lds(16B) staging, unpadded
// 64B LDS rows. fused=1: grid (64,24), seg = y>>3 picks {Q,K,V}; V scatters to
// Vt[b,h,d,s] with packed 8B stores. fused=0: grid (64,8), fp32 output.
// q_scale: folded into the Q output (seg==0) so flash_attn's softmax needs no
// per-element scale multiply.
// ---------------------------------------------------------------------------
__global__ __launch_bounds__(256)
void gemm_bt(const bf16* __restrict__ A,
             const bf16* __restrict__ W0, const bf16* __restrict__ W1, const bf16* __restrict__ W2,
             const float* __restrict__ b0, const float* __restrict__ b1, const float* __restrict__ b2,
             void* __restrict__ d0, void* __restrict__ d1, void* __restrict__ d2,
             int fused, float q_scale)
{
    __shared__ bf16 al[128 * 32];
    __shared__ bf16 bl[128 * 32];

    int seg, mode, n0;
    if (fused) { seg = blockIdx.y >> 3; n0 = (blockIdx.y & 7) * 128; mode = (seg == 2) ? 1 : 0; }
    else       { seg = 0;              n0 = blockIdx.y * 128;        mode = 2; }
    const bf16*  W    = seg == 0 ? W0 : (seg == 1 ? W1 : W2);
    const float* bias = seg == 0 ? b0 : (seg == 1 ? b1 : b2);
    void*        C    = seg == 0 ? d0 : (seg == 1 ? d1 : d2);
    const float  osc  = (fused && seg == 0) ? q_scale : 1.0f;

    const int tid  = threadIdx.x;
    const int lane = tid & 63;
    const int w    = tid >> 6;
    const int quad = lane >> 4;
    const int l16  = lane & 15;
    const int wm   = (w >> 1) * 64;
    const int wn   = (w & 1) * 64;
    const int m0   = blockIdx.x * 128;

    f32x4 acc[4][4] = {};

    for (int k0 = 0; k0 < EMB; k0 += 32) {
        #pragma unroll
        for (int c = 0; c < 2; ++c) {
            int idx = c * 256 + tid;            // LDS addr = idx*16B: uniform base + lane*16 per wave
            int row = idx >> 2, kc = idx & 3;
            gload_lds16(A + (size_t)(m0 + row) * EMB + k0 + kc * 8, &al[idx * 8]);
            gload_lds16(W + (size_t)(n0 + row) * EMB + k0 + kc * 8, &bl[idx * 8]);
        }
        __syncthreads();

        bf16x8 afrag[4], bfrag[4];
        #pragma unroll
        for (int t = 0; t < 4; ++t)
            afrag[t] = *(const bf16x8*)&al[(wm + t * 16 + l16) * 32 + quad * 8];
        #pragma unroll
        for (int t = 0; t < 4; ++t)
            bfrag[t] = *(const bf16x8*)&bl[(wn + t * 16 + l16) * 32 + quad * 8];

        #pragma unroll
        for (int mt = 0; mt < 4; ++mt)
            #pragma unroll
            for (int nt = 0; nt < 4; ++nt)
                acc[mt][nt] = MFMA_BF16(afrag[mt], bfrag[nt], acc[mt][nt]);

        __syncthreads();
    }

    // epilogue: C-layout row = quad*4+r, col = l16 (m89-verified)
    #pragma unroll
    for (int mt = 0; mt < 4; ++mt) {
        #pragma unroll
        for (int nt = 0; nt < 4; ++nt) {
            int col = n0 + wn + nt * 16 + l16;
            float bv = bias[col];
            int row0 = m0 + wm + mt * 16 + quad * 4;
            if (mode == 1) {
                int bb = row0 >> 11, s0 = row0 & 2047;
                int hh = col >> 6,   d  = col & 63;
                bf16x4 pk;
                #pragma unroll
                for (int r = 0; r < 4; ++r) pk[r] = (bf16)(acc[mt][nt][r] + bv);
                *(bf16x4*)((bf16*)C + (size_t)((bb * NHEAD + hh) * HDIM + d) * S_LEN + s0) = pk;
            } else if (mode == 0) {
                #pragma unroll
                for (int r = 0; r < 4; ++r)
                    ((bf16*)C)[(size_t)(row0 + r) * EMB + col] = (bf16)((acc[mt][nt][r] + bv) * osc);
            } else {
                #pragma unroll
                for (int r = 0; r < 4; ++r)
                    ((float*)C)[(size_t)(row0 + r) * EMB + col] = acc[mt][nt][r] + bv;
            }
        }
    }
}

// ---------------------------------------------------------------------------
// Flash attention, S^T orientation: sacc = mfma(kf, qf) so C-layout puts
// query on l16 (lane) and keys on (nt, quad*4+r) regs. Q is PRE-SCALED by
// 1/sqrt(64)*log2e in the QKV GEMM, so softmax works on raw sacc.
//
// Round-2 lesson (counters): VGPR 136 (>128 cliff) halved occupancy
// (23->11.8%), dur 251->359us, despite zero spills. All pipes idle
// (Mfma 7.8 / VALU 19 / HBM 5.5%) => purely latency-bound; resident waves
// is the only lever, and registers bound resident waves.
//
// This round: KVBLK 128 -> 64. sacc[8][2] (64 regs) -> sacc[4][2] (32 regs);
// peak live ~110 < 128. Same total MFMA / K / V traffic; online-softmax
// bookkeeping runs 32x instead of 16x but defer-max makes it ~10 VALU ops
// per tile. plds shrinks to 16KB (LDS total ~20.6KB -> LDS allows 7 blk/CU,
// registers are the sole occupancy limiter). allvalid bias add is now a
// separate pre-pass (single max loop -> less code dup, lower reg pressure).
//
// Kept: allvalid skip, defer-max (THR=8), per-lane partial l, XOR-swizzled
// plds (row&7)<<4, s_setprio around MFMA clusters, no in-loop __syncthreads
// (all LDS wave-private; wave64 lockstep).
// Grid (S/128, H, B), 256 thr = 4 waves; wave owns 32 query rows.
// ---------------------------------------------------------------------------
__global__ __launch_bounds__(256)
void flash_attn(const bf16* __restrict__ qg, const bf16* __restrict__ kg,
                const bf16* __restrict__ vtg, const int* __restrict__ maskg,
                bf16* __restrict__ ctx)
{
    __shared__ bf16  plds[128 * 64];      // 128B rows, XOR-swizzled, 16KB
    __shared__ bf16  bias_lds[2048];      // additive mask bias (bf16), masked path only
    __shared__ float stat_lds[4][32];     // per-wave alpha / inv-l broadcast

    const int tid  = threadIdx.x;
    const int lane = tid & 63;
    const int w    = tid >> 6;
    const int quad = lane >> 4;
    const int l16  = lane & 15;
    const int b    = blockIdx.z;
    const int h    = blockIdx.y;
    const int q0   = blockIdx.x * 128;

    // mask -> bf16 additive bias in LDS (each thread covers 8 keys) + allvalid
    int ok;
    {
        int i = tid * 8;
        i32x4 m0v = *(const i32x4*)(maskg + b * S_LEN + i);
        i32x4 m1v = *(const i32x4*)(maskg + b * S_LEN + i + 4);
        bf16x8 bb;
        ok = 1;
        #pragma unroll
        for (int r = 0; r < 4; ++r) {
            ok &= (m0v[r] != 0) & (m1v[r] != 0);
            bb[r]     = m0v[r] ? (bf16)0.f : (bf16)(-3.0e38f);
            bb[4 + r] = m1v[r] ? (bf16)0.f : (bf16)(-3.0e38f);
        }
        *(bf16x8*)&bias_lds[i] = bb;
    }
    const int allvalid = __syncthreads_and(ok);

    // Q fragments (B-operand: n=query=l16, k=quad*8+j), resident all kernel
    bf16x8 qf[2][2];
    #pragma unroll
    for (int mt = 0; mt < 2; ++mt)
        #pragma unroll
        for (int ks = 0; ks < 2; ++ks) {
            int row = b * S_LEN + q0 + w * 32 + mt * 16 + l16;
            qf[mt][ks] = *(const bf16x8*)(qg + (size_t)row * EMB + h * HDIM + ks * 32 + quad * 8);
        }

    float mrow[2]  = {-1e30f, -1e30f};
    float lpart[2] = {0.f, 0.f};          // per-lane partial row-sum (quad-partial)
    f32x4 oacc[2][4] = {};

    for (int kt = 0; kt < 32; ++kt) {
        const int k0 = kt * 64;

        // ---- S^T = K Q^T: C[key=quad*4+r][query=l16], 4 key-subtiles ----
        f32x4 sacc[4][2] = {};
        __builtin_amdgcn_s_setprio(1);
        #pragma unroll
        for (int nt = 0; nt < 4; ++nt) {
            int krow = b * S_LEN + k0 + nt * 16 + l16;
            #pragma unroll
            for (int ks = 0; ks < 2; ++ks) {
                bf16x8 kf = *(const bf16x8*)(kg + (size_t)krow * EMB + h * HDIM + ks * 32 + quad * 8);
                sacc[nt][0] = MFMA_BF16(kf, qf[0][ks], sacc[nt][0]);
                sacc[nt][1] = MFMA_BF16(kf, qf[1][ks], sacc[nt][1]);
            }
        }
        __builtin_amdgcn_s_setprio(0);

        // ---- optional mask bias pre-pass (rare), then single max loop ----
        if (!allvalid) {
            #pragma unroll
            for (int nt = 0; nt < 4; ++nt) {
                bf16x4 b4 = *(const bf16x4*)&bias_lds[k0 + nt * 16 + quad * 4];
                #pragma unroll
                for (int mt = 0; mt < 2; ++mt)
                    #pragma unroll
                    for (int r = 0; r < 4; ++r)
                        sacc[nt][mt][r] += (float)b4[r];
            }
        }
        float rmax[2] = {-3.0e38f, -3.0e38f};
        #pragma unroll
        for (int nt = 0; nt < 4; ++nt)
            #pragma unroll
            for (int mt = 0; mt < 2; ++mt)
                rmax[mt] = fmaxf(rmax[mt],
                                 fmaxf(fmaxf(sacc[nt][mt][0], sacc[nt][mt][1]),
                                       fmaxf(sacc[nt][mt][2], sacc[nt][mt][3])));
        #pragma unroll
        for (int mt = 0; mt < 2; ++mt) {
            rmax[mt] = fmaxf(rmax[mt], __shfl_xor(rmax[mt], 16));
            rmax[mt] = fmaxf(rmax[mt], __shfl_xor(rmax[mt], 32));
        }

        // ---- defer-max: rescale only when running max grew by > 8 ----
        if (!__all((rmax[0] <= mrow[0] + 8.f) & (rmax[1] <= mrow[1] + 8.f))) {
            float alpha[2];
            #pragma unroll
            for (int mt = 0; mt < 2; ++mt) {
                float mnew = fmaxf(mrow[mt], rmax[mt]);
                alpha[mt] = __builtin_amdgcn_exp2f(mrow[mt] - mnew);
                mrow[mt]  = mnew;
                lpart[mt] *= alpha[mt];
            }
            if (quad == 0) { stat_lds[w][l16] = alpha[0]; stat_lds[w][16 + l16] = alpha[1]; }
            #pragma unroll
            for (int mt2 = 0; mt2 < 2; ++mt2) {
                f32x4 a4 = *(const f32x4*)&stat_lds[w][mt2 * 16 + quad * 4];
                #pragma unroll
                for (int dt = 0; dt < 4; ++dt)
                    #pragma unroll
                    for (int r = 0; r < 4; ++r)
                        oacc[mt2][dt][r] *= a4[r];
            }
        }

        // ---- P = exp2(S - m), packed bf16 writes to swizzled LDS ----
        #pragma unroll
        for (int nt = 0; nt < 4; ++nt)
            #pragma unroll
            for (int mt = 0; mt < 2; ++mt) {
                bf16x4 pk;
                #pragma unroll
                for (int r = 0; r < 4; ++r) {
                    float p = __builtin_amdgcn_exp2f(sacc[nt][mt][r] - mrow[mt]);
                    lpart[mt] += p;
                    pk[r] = (bf16)p;
                }
                int byte = (w * 32 + mt * 16 + l16) * 128 + nt * 32 + quad * 8;
                byte ^= (l16 & 7) << 4;
                *(bf16x4*)((char*)plds + byte) = pk;
            }

        // ---- O += P V  (P A-operand from swizzled LDS b128, Vt NT B-operand) ----
        __builtin_amdgcn_s_setprio(1);
        #pragma unroll
        for (int ks = 0; ks < 2; ++ks) {
            int byte0 = (w * 32 + l16) * 128 + ks * 64 + quad * 16;
            byte0 ^= (l16 & 7) << 4;
            bf16x8 pf0 = *(const bf16x8*)((char*)plds + byte0);
            bf16x8 pf1 = *(const bf16x8*)((char*)plds + byte0 + 16 * 128);
            #pragma unroll
            for (int dt = 0; dt < 4; ++dt) {
                bf16x8 vf = *(const bf16x8*)(vtg + (size_t)((b * NHEAD + h) * HDIM + dt * 16 + l16) * S_LEN
                                             + k0 + ks * 32 + quad * 8);
                oacc[0][dt] = MFMA_BF16(pf0, vf, oacc[0][dt]);
                oacc[1][dt] = MFMA_BF16(pf1, vf, oacc[1][dt]);
            }
        }
        __builtin_amdgcn_s_setprio(0);
    }

    // ---- final cross-quad row-sum reduce, 1/l broadcast, store ctx[b,s,h,d] ----
    float lrow[2];
    #pragma unroll
    for (int mt = 0; mt < 2; ++mt) {
        float s = lpart[mt];
        s += __shfl_xor(s, 16);
        s += __shfl_xor(s, 32);
        lrow[mt] = s;
    }
    if (quad == 0) {
        stat_lds[w][l16]      = lrow[0] > 0.f ? 1.f / lrow[0] : 0.f;
        stat_lds[w][16 + l16] = lrow[1] > 0.f ? 1.f / lrow[1] : 0.f;
    }
    #pragma unroll
    for (int mt2 = 0; mt2 < 2; ++mt2) {
        f32x4 inv4 = *(const f32x4*)&stat_lds[w][mt2 * 16 + quad * 4];
        #pragma unroll
        for (int r = 0; r < 4; ++r) {
            size_t row = (size_t)(b * S_LEN + q0 + w * 32 + mt2 * 16 + quad * 4 + r);
            #pragma unroll
            for (int dt = 0; dt < 4; ++dt)
                ctx[row * EMB + h * HDIM + dt * 16 + l16] = (bf16)(oacc[mt2][dt][r] * inv4[r]);
        }
    }
}

extern "C" void kernel_launch(void* const* d_in, const int* in_sizes, int n_in,
                              void* d_out, int out_size, void* d_ws, size_t ws_size,
                              hipStream_t stream)
{
    const float* x   = (const float*)d_in[0];
    const int*  mask = (const int*)d_in[1];
    const float* Wq  = (const float*)d_in[2];
    const float* bq  = (const float*)d_in[3];
    const float* Wk  = (const float*)d_in[4];
    const float* bk  = (const float*)d_in[5];
    const float* Wv  = (const float*)d_in[6];
    const float* bv  = (const float*)d_in[7];
    const float* Wo  = (const float*)d_in[8];
    const float* bo  = (const float*)d_in[9];
    (void)in_sizes; (void)n_in; (void)out_size; (void)ws_size;

    const size_t me = (size_t)NTOK * EMB;    // 8.4M
    const size_t we = (size_t)EMB * EMB;     // 1M
    bf16* xb  = (bf16*)d_ws;
    bf16* qb  = xb  + me;
    bf16* kb  = qb  + me;
    bf16* vt  = kb  + me;     // V transposed [b,h,d,s]
    bf16* wqb = vt  + me;
    bf16* wkb = wqb + we;
    bf16* wvb = wkb + we;
    bf16* wob = wvb + we;
    bf16* cx  = xb;           // alias: xb consumed by qkv gemm before flash writes cx

    cvt_f32_bf16<<<(int)(me / 4 / 256), 256, 0, stream>>>(x,  xb,  (int)(me / 4));
    cvt_f32_bf16<<<(int)(we / 4 / 256), 256, 0, stream>>>(Wq, wqb, (int)(we / 4));
    cvt_f32_bf16<<<(int)(we / 4 / 256), 256, 0, stream>>>(Wk, wkb, (int)(we / 4));
    cvt_f32_bf16<<<(int)(we / 4 / 256), 256, 0, stream>>>(Wv, wvb, (int)(we / 4));
    cvt_f32_bf16<<<(int)(we / 4 / 256), 256, 0, stream>>>(Wo, wob, (int)(we / 4));

    // q_scale = 1/sqrt(HDIM) * log2(e), folded into Q so flash softmax is scale-free
    gemm_bt<<<dim3(NTOK / 128, 24), 256, 0, stream>>>(
        xb, wqb, wkb, wvb, bq, bk, bv, qb, kb, vt, 1, 0.18033688011112042f);

    flash_attn<<<dim3(S_LEN / 128, NHEAD, BATCH), 256, 0, stream>>>(qb, kb, vt, mask, cx);

    gemm_bt<<<dim3(NTOK / 128, EMB / 128), 256, 0, stream>>>(
        cx, wob, wob, wob, bo, bo, bo, d_out, d_out, d_out, 0, 1.0f);
}

// Round 4
// 430.851 us; speedup vs baseline: 1.2769x; 1.0796x over previous
//
#include <hip/hip_runtime.h>

typedef __bf16 bf16;
typedef __attribute__((ext_vector_type(2))) bf16 bf16x2;
typedef __attribute__((ext_vector_type(4))) bf16 bf16x4;
typedef __attribute__((ext_vector_type(8))) bf16 bf16x8;
typedef __attribute__((ext_vector_type(4))) float f32x4;
typedef __attribute__((ext_vector_type(16))) float f32x16;
typedef __attribute__((ext_vector_type(4))) int i32x4;
typedef __attribute__((ext_vector_type(2))) int i32x2;

#define MFMA_BF16(a, b, c) __builtin_amdgcn_mfma_f32_16x16x32_bf16((a), (b), (c), 0, 0, 0)
#define MFMA32(a, b, c)    __builtin_amdgcn_mfma_f32_32x32x16_bf16((a), (b), (c), 0, 0, 0)

constexpr int S_LEN = 2048;
constexpr int EMB   = 1024;
constexpr int NHEAD = 16;
constexpr int HDIM  = 64;
constexpr int BATCH = 4;
constexpr int NTOK  = BATCH * S_LEN;   // 8192

// async global->LDS, 16B per lane (m97 pattern: LDS dest must be uniform base + lane*16)
__device__ __forceinline__ void gload_lds16(const bf16* g, bf16* l) {
    __builtin_amdgcn_global_load_lds(
        (const __attribute__((address_space(1))) void*)g,
        (__attribute__((address_space(3))) void*)l, 16, 0, 0);
}

// pack two f32 -> one dword of 2 bf16 (compiler emits v_cvt_pk_bf16_f32; m240: don't hand-asm)
__device__ __forceinline__ int pkbf(float a, float b) {
    bf16x2 t; t[0] = (bf16)a; t[1] = (bf16)b;
    return __builtin_bit_cast(int, t);
}

// half-wave swap primitive (T12). Semantics: r[0] = {a[0:31], b[0:31]}, r[1] = {a[32:63], b[32:63]}.
#if __has_builtin(__builtin_amdgcn_permlane32_swap)
__device__ __forceinline__ i32x2 permswap(int a, int b) {
    return __builtin_amdgcn_permlane32_swap(a, b, false, false);
}
#else
__device__ __forceinline__ i32x2 permswap(int a, int b) {
    int as = __shfl_xor(a, 32);
    int bs = __shfl_xor(b, 32);
    int hx_ = (threadIdx.x >> 5) & 1;
    i32x2 r;
    r[0] = hx_ ? bs : a;
    r[1] = hx_ ? b : as;
    return r;
}
#endif

// ---------------------------------------------------------------------------
// fp32 -> bf16 elementwise convert (n4 = n/4)
// ---------------------------------------------------------------------------
__global__ __launch_bounds__(256)
void cvt_f32_bf16(const float* __restrict__ src, bf16* __restrict__ dst, int n4) {
    int i = blockIdx.x * 256 + threadIdx.x;
    if (i < n4) {
        f32x4 v = ((const f32x4*)src)[i];
        bf16x4 o;
        o[0] = (bf16)v[0]; o[1] = (bf16)v[1]; o[2] = (bf16)v[2]; o[3] = (bf16)v[3];
        ((bf16x4*)dst)[i] = o;
    }
}

// ---------------------------------------------------------------------------
// NT GEMM, m97 structure (unchanged from round 3; known-good).
// ---------------------------------------------------------------------------
__global__ __launch_bounds__(256)
void gemm_bt(const bf16* __restrict__ A,
             const bf16* __restrict__ W0, const bf16* __restrict__ W1, const bf16* __restrict__ W2,
             const float* __restrict__ b0, const float* __restrict__ b1, const float* __restrict__ b2,
             void* __restrict__ d0, void* __restrict__ d1, void* __restrict__ d2,
             int fused, float q_scale)
{
    __shared__ bf16 al[128 * 32];
    __shared__ bf16 bl[128 * 32];

    int seg, mode, n0;
    if (fused) { seg = blockIdx.y >> 3; n0 = (blockIdx.y & 7) * 128; mode = (seg == 2) ? 1 : 0; }
    else       { seg = 0;              n0 = blockIdx.y * 128;        mode = 2; }
    const bf16*  W    = seg == 0 ? W0 : (seg == 1 ? W1 : W2);
    const float* bias = seg == 0 ? b0 : (seg == 1 ? b1 : b2);
    void*        C    = seg == 0 ? d0 : (seg == 1 ? d1 : d2);
    const float  osc  = (fused && seg == 0) ? q_scale : 1.0f;

    const int tid  = threadIdx.x;
    const int lane = tid & 63;
    const int w    = tid >> 6;
    const int quad = lane >> 4;
    const int l16  = lane & 15;
    const int wm   = (w >> 1) * 64;
    const int wn   = (w & 1) * 64;
    const int m0   = blockIdx.x * 128;

    f32x4 acc[4][4] = {};

    for (int k0 = 0; k0 < EMB; k0 += 32) {
        #pragma unroll
        for (int c = 0; c < 2; ++c) {
            int idx = c * 256 + tid;            // LDS addr = idx*16B: uniform base + lane*16 per wave
            int row = idx >> 2, kc = idx & 3;
            gload_lds16(A + (size_t)(m0 + row) * EMB + k0 + kc * 8, &al[idx * 8]);
            gload_lds16(W + (size_t)(n0 + row) * EMB + k0 + kc * 8, &bl[idx * 8]);
        }
        __syncthreads();

        bf16x8 afrag[4], bfrag[4];
        #pragma unroll
        for (int t = 0; t < 4; ++t)
            afrag[t] = *(const bf16x8*)&al[(wm + t * 16 + l16) * 32 + quad * 8];
        #pragma unroll
        for (int t = 0; t < 4; ++t)
            bfrag[t] = *(const bf16x8*)&bl[(wn + t * 16 + l16) * 32 + quad * 8];

        #pragma unroll
        for (int mt = 0; mt < 4; ++mt)
            #pragma unroll
            for (int nt = 0; nt < 4; ++nt)
                acc[mt][nt] = MFMA_BF16(afrag[mt], bfrag[nt], acc[mt][nt]);

        __syncthreads();
    }

    // epilogue: C-layout row = quad*4+r, col = l16 (m89-verified)
    #pragma unroll
    for (int mt = 0; mt < 4; ++mt) {
        #pragma unroll
        for (int nt = 0; nt < 4; ++nt) {
            int col = n0 + wn + nt * 16 + l16;
            float bv = bias[col];
            int row0 = m0 + wm + mt * 16 + quad * 4;
            if (mode == 1) {
                int bb = row0 >> 11, s0 = row0 & 2047;
                int hh = col >> 6,   d  = col & 63;
                bf16x4 pk;
                #pragma unroll
                for (int r = 0; r < 4; ++r) pk[r] = (bf16)(acc[mt][nt][r] + bv);
                *(bf16x4*)((bf16*)C + (size_t)((bb * NHEAD + hh) * HDIM + d) * S_LEN + s0) = pk;
            } else if (mode == 0) {
                #pragma unroll
                for (int r = 0; r < 4; ++r)
                    ((bf16*)C)[(size_t)(row0 + r) * EMB + col] = (bf16)((acc[mt][nt][r] + bv) * osc);
            } else {
                #pragma unroll
                for (int r = 0; r < 4; ++r)
                    ((float*)C)[(size_t)(row0 + r) * EMB + col] = acc[mt][nt][r] + bv;
            }
        }
    }
}

// ---------------------------------------------------------------------------
// Flash attention, m214-style 32x32 structure. Q PRE-SCALED by 1/8*log2e.
//
// Round-3 lesson: occupancy was never VGPR-limited at <=128 (grid supplies
// exactly 4 blocks/CU); the kernel is latency-bound on the serialized
// per-tile chain (Mfma 10 / VALU 24 / HBM 7% => ~65% stall). So this round
// removes serial latency instead of chasing residency:
//  - 32x32x16 MFMA, swapped QK^T: sacc C-layout col=lane&31=query,
//    row=crow(r,hx)=(r&3)+8*(r>>2)+4*hx = key (m74/m101-verified).
//    Softmax reduce = 15 in-lane fmax + ONE shfl_xor(32) (was 4 shuffles).
//    mrow/lpart are per-lane scalars.
//  - In-register P->PV (T12): 8 cvt_pk + 4 permlane32_swap per 32-key tile
//    build the PV A-operand (row=query=lane&31, k=key=hx*8+j) directly from
//    sacc regs. P LDS round-trip GONE (plds gone, bank conflicts -> ~0).
//  - K reg-prefetch across iterations (T14): kfa/kfb ping-pong, named vars
//    (rule #20), loop unrolled x2. V issued after defer-check, latency
//    hidden under the P-pack VALU.
//  - oacc rescale (rare, defer-max THR=8) and final 1/l use stat_lds
//    broadcast (query is reg-indexed in oacc rows); wave-private, lockstep.
// LDS: 4.6KB. Grid (S/128, H, B), 256 thr = 4 waves; wave owns 32 q-rows.
// ---------------------------------------------------------------------------
__global__ __launch_bounds__(256)
void flash_attn(const bf16* __restrict__ qg, const bf16* __restrict__ kg,
                const bf16* __restrict__ vtg, const int* __restrict__ maskg,
                bf16* __restrict__ ctx)
{
    __shared__ bf16  bias_lds[2048];      // additive mask bias (bf16), masked path only
    __shared__ float stat_lds[4][32];     // per-wave alpha / inv-l broadcast

    const int tid  = threadIdx.x;
    const int lane = tid & 63;
    const int w    = tid >> 6;
    const int l32  = lane & 31;
    const int hx   = lane >> 5;
    const int b    = blockIdx.z;
    const int h    = blockIdx.y;
    const int q0   = blockIdx.x * 128;

    // mask -> bf16 additive bias in LDS (each thread covers 8 keys) + allvalid
    int ok;
    {
        int i = tid * 8;
        i32x4 m0v = *(const i32x4*)(maskg + b * S_LEN + i);
        i32x4 m1v = *(const i32x4*)(maskg + b * S_LEN + i + 4);
        bf16x8 bb;
        ok = 1;
        #pragma unroll
        for (int r = 0; r < 4; ++r) {
            ok &= (m0v[r] != 0) & (m1v[r] != 0);
            bb[r]     = m0v[r] ? (bf16)0.f : (bf16)(-3.0e38f);
            bb[4 + r] = m1v[r] ? (bf16)0.f : (bf16)(-3.0e38f);
        }
        *(bf16x8*)&bias_lds[i] = bb;
    }
    const int allvalid = __syncthreads_and(ok);

    // Q fragments (B-operand: col=query=l32, k = c*16 + hx*8 + j), resident
    bf16x8 qf[4];
    {
        const bf16* qrow = qg + (size_t)(b * S_LEN + q0 + w * 32 + l32) * EMB + h * HDIM + hx * 8;
        qf[0] = *(const bf16x8*)(qrow);
        qf[1] = *(const bf16x8*)(qrow + 16);
        qf[2] = *(const bf16x8*)(qrow + 32);
        qf[3] = *(const bf16x8*)(qrow + 48);
    }

    const bf16* kbase = kg + (size_t)(b * S_LEN + l32) * EMB + h * HDIM + hx * 8;
    const bf16* vb0   = vtg + (size_t)((b * NHEAD + h) * HDIM + l32) * S_LEN + hx * 8;
    const bf16* vb1   = vb0 + (size_t)32 * S_LEN;

    float mrow = -1e30f, lpart = 0.f;
    f32x16 o0, o1;
    #pragma unroll
    for (int r = 0; r < 16; ++r) { o0[r] = 0.f; o1[r] = 0.f; }

#define LOADK(DST, KTI) { const bf16* kp_ = kbase + (size_t)(KTI) * 32 * EMB;      \
    DST[0] = *(const bf16x8*)(kp_);      DST[1] = *(const bf16x8*)(kp_ + 16);      \
    DST[2] = *(const bf16x8*)(kp_ + 32); DST[3] = *(const bf16x8*)(kp_ + 48); }

#define BODY(KF, KT) {                                                             \
    const int k0_ = (KT) * 32;                                                     \
    f32x16 s_;                                                                     \
    _Pragma("unroll") for (int r_ = 0; r_ < 16; ++r_) s_[r_] = 0.f;                \
    __builtin_amdgcn_s_setprio(1);                                                 \
    s_ = MFMA32(KF[0], qf[0], s_); s_ = MFMA32(KF[1], qf[1], s_);                  \
    s_ = MFMA32(KF[2], qf[2], s_); s_ = MFMA32(KF[3], qf[3], s_);                  \
    __builtin_amdgcn_s_setprio(0);                                                 \
    if (!allvalid) {                                                               \
        _Pragma("unroll") for (int s4_ = 0; s4_ < 4; ++s4_) {                      \
            bf16x4 b4_ = *(const bf16x4*)&bias_lds[k0_ + s4_ * 8 + hx * 4];        \
            _Pragma("unroll") for (int t_ = 0; t_ < 4; ++t_)                       \
                s_[4 * s4_ + t_] += (float)b4_[t_];                                \
        }                                                                          \
    }                                                                              \
    float rmax_ = s_[0];                                                           \
    _Pragma("unroll") for (int r_ = 1; r_ < 16; ++r_) rmax_ = fmaxf(rmax_, s_[r_]);\
    rmax_ = fmaxf(rmax_, __shfl_xor(rmax_, 32));                                   \
    if (!__all(rmax_ <= mrow + 8.f)) {                                             \
        float mnew_  = fmaxf(mrow, rmax_);                                         \
        float alpha_ = __builtin_amdgcn_exp2f(mrow - mnew_);                       \
        mrow = mnew_; lpart *= alpha_;                                             \
        if (hx == 0) stat_lds[w][l32] = alpha_;                                    \
        _Pragma("unroll") for (int s4_ = 0; s4_ < 4; ++s4_) {                      \
            f32x4 a4_ = *(const f32x4*)&stat_lds[w][s4_ * 8 + hx * 4];             \
            _Pragma("unroll") for (int t_ = 0; t_ < 4; ++t_) {                     \
                o0[4 * s4_ + t_] *= a4_[t_]; o1[4 * s4_ + t_] *= a4_[t_];          \
            }                                                                      \
        }                                                                          \
    }                                                                              \
    bf16x8 vf00 = *(const bf16x8*)(vb0 + k0_);                                     \
    bf16x8 vf10 = *(const bf16x8*)(vb0 + k0_ + 16);                                \
    bf16x8 vf01 = *(const bf16x8*)(vb1 + k0_);                                     \
    bf16x8 vf11 = *(const bf16x8*)(vb1 + k0_ + 16);                                \
    bf16x8 pa0, pa1;                                                               \
    {                                                                              \
        float p_[8];                                                               \
        _Pragma("unroll") for (int r_ = 0; r_ < 8; ++r_) {                         \
            p_[r_] = __builtin_amdgcn_exp2f(s_[r_] - mrow); lpart += p_[r_];       \
        }                                                                          \
        i32x2 r0_ = permswap(pkbf(p_[0], p_[1]), pkbf(p_[4], p_[5]));              \
        i32x2 r1_ = permswap(pkbf(p_[2], p_[3]), pkbf(p_[6], p_[7]));              \
        i32x4 fw_; fw_[0] = r0_[0]; fw_[1] = r1_[0]; fw_[2] = r0_[1]; fw_[3] = r1_[1]; \
        pa0 = __builtin_bit_cast(bf16x8, fw_);                                     \
    }                                                                              \
    {                                                                              \
        float p_[8];                                                               \
        _Pragma("unroll") for (int r_ = 0; r_ < 8; ++r_) {                         \
            p_[r_] = __builtin_amdgcn_exp2f(s_[8 + r_] - mrow); lpart += p_[r_];   \
        }                                                                          \
        i32x2 r0_ = permswap(pkbf(p_[0], p_[1]), pkbf(p_[4], p_[5]));              \
        i32x2 r1_ = permswap(pkbf(p_[2], p_[3]), pkbf(p_[6], p_[7]));              \
        i32x4 fw_; fw_[0] = r0_[0]; fw_[1] = r1_[0]; fw_[2] = r0_[1]; fw_[3] = r1_[1]; \
        pa1 = __builtin_bit_cast(bf16x8, fw_);                                     \
    }                                                                              \
    __builtin_amdgcn_s_setprio(1);                                                 \
    o0 = MFMA32(pa0, vf00, o0); o1 = MFMA32(pa0, vf01, o1);                        \
    o0 = MFMA32(pa1, vf10, o0); o1 = MFMA32(pa1, vf11, o1);                        \
    __builtin_amdgcn_s_setprio(0);                                                 \
}

    bf16x8 kfa[4], kfb[4];
    LOADK(kfa, 0)
    for (int kt = 0; kt < 64; kt += 2) {
        LOADK(kfb, kt + 1)
        BODY(kfa, kt)
        int ktn = (kt + 2 < 64) ? kt + 2 : 63;   // last prefetch clamped (redundant, in-bounds)
        LOADK(kfa, ktn)
        BODY(kfb, kt + 1)
    }

#undef BODY
#undef LOADK

    // ---- epilogue: cross-half l reduce, 1/l broadcast, store ctx[b,s,h,d] ----
    float lrow = lpart + __shfl_xor(lpart, 32);
    float inv  = lrow > 0.f ? 1.f / lrow : 0.f;
    if (hx == 0) stat_lds[w][l32] = inv;
    #pragma unroll
    for (int s4 = 0; s4 < 4; ++s4) {
        f32x4 i4 = *(const f32x4*)&stat_lds[w][s4 * 8 + hx * 4];
        #pragma unroll
        for (int t = 0; t < 4; ++t) {
            size_t row = (size_t)(b * S_LEN + q0 + w * 32 + s4 * 8 + hx * 4 + t);
            bf16* cp = ctx + row * EMB + h * HDIM + l32;
            cp[0]  = (bf16)(o0[4 * s4 + t] * i4[t]);
            cp[32] = (bf16)(o1[4 * s4 + t] * i4[t]);
        }
    }
}

extern "C" void kernel_launch(void* const* d_in, const int* in_sizes, int n_in,
                              void* d_out, int out_size, void* d_ws, size_t ws_size,
                              hipStream_t stream)
{
    const float* x   = (const float*)d_in[0];
    const int*  mask = (const int*)d_in[1];
    const float* Wq  = (const float*)d_in[2];
    const float* bq  = (const float*)d_in[3];
    const float* Wk  = (const float*)d_in[4];
    const float* bk  = (const float*)d_in[5];
    const float* Wv  = (const float*)d_in[6];
    const float* bv  = (const float*)d_in[7];
    const float* Wo  = (const float*)d_in[8];
    const float* bo  = (const float*)d_in[9];
    (void)in_sizes; (void)n_in; (void)out_size; (void)ws_size;

    const size_t me = (size_t)NTOK * EMB;    // 8.4M
    const size_t we = (size_t)EMB * EMB;     // 1M
    bf16* xb  = (bf16*)d_ws;
    bf16* qb  = xb  + me;
    bf16* kb  = qb  + me;
    bf16* vt  = kb  + me;     // V transposed [b,h,d,s]
    bf16* wqb = vt  + me;
    bf16* wkb = wqb + we;
    bf16* wvb = wkb + we;
    bf16* wob = wvb + we;
    bf16* cx  = xb;           // alias: xb consumed by qkv gemm before flash writes cx

    cvt_f32_bf16<<<(int)(me / 4 / 256), 256, 0, stream>>>(x,  xb,  (int)(me / 4));
    cvt_f32_bf16<<<(int)(we / 4 / 256), 256, 0, stream>>>(Wq, wqb, (int)(we / 4));
    cvt_f32_bf16<<<(int)(we / 4 / 256), 256, 0, stream>>>(Wk, wkb, (int)(we / 4));
    cvt_f32_bf16<<<(int)(we / 4 / 256), 256, 0, stream>>>(Wv, wvb, (int)(we / 4));
    cvt_f32_bf16<<<(int)(we / 4 / 256), 256, 0, stream>>>(Wo, wob, (int)(we / 4));

    // q_scale = 1/sqrt(HDIM) * log2(e), folded into Q so flash softmax is scale-free
    gemm_bt<<<dim3(NTOK / 128, 24), 256, 0, stream>>>(
        xb, wqb, wkb, wvb, bq, bk, bv, qb, kb, vt, 1, 0.18033688011112042f);

    flash_attn<<<dim3(S_LEN / 128, NHEAD, BATCH), 256, 0, stream>>>(qb, kb, vt, mask, cx);

    gemm_bt<<<dim3(NTOK / 128, EMB / 128), 256, 0, stream>>>(
        cx, wob, wob, wob, bo, bo, bo, d_out, d_out, d_out, 0, 1.0f);
}